// Round 22
// baseline (162.313 us; speedup 1.0000x reference)
//
#include <hip/hip_runtime.h>
#include <hip/hip_fp16.h>
#include <stdint.h>

constexpr int Bn = 8, Nn = 4096, Dn = 128, Cn = 256, Kn = 16;

// ---------------- Kernel A0: pack xyz -> float4 (2x, 2y, 2z, -xx) ----------------
// xx = ((x*x)+(y*y))+(z*z) with the reference rounding; 2x/2y/2z are exact (x2).
__global__ __launch_bounds__(256) void pack_kernel(const float* __restrict__ xyz, float4* __restrict__ xyzw)
{
    const int p = blockIdx.x * 256 + threadIdx.x;   // 32768 points
    const float x = xyz[p * 3 + 0], y = xyz[p * 3 + 1], z = xyz[p * 3 + 2];
    const float xx = __fadd_rn(__fadd_rn(__fmul_rn(x, x), __fmul_rn(y, y)), __fmul_rn(z, z));
    xyzw[p] = make_float4(2.0f * x, 2.0f * y, 2.0f * z, -xx);
}

// exact pd in 5 ops (reference-matching formula of rounds 3-21)
__device__ __forceinline__ float pd5(const float4 Qu, const float4 P)
{
    const float inner2 = __builtin_fmaf(Qu.z, P.z, __builtin_fmaf(Qu.y, P.y, __fmul_rn(Qu.x, P.x)));
    return __fadd_rn(__fadd_rn(Qu.w, inner2), P.w);
}

// ---------------- Kernel A: exact KNN, L2-direct, 8 queries/wave ----------------
// 512 threads = 8 waves x 8 queries = 64 rows/block; 512 blocks. Candidates stream from
// L2 (xyzw = 512KB, resident in every XCD L2). r21 profile: VGPR=24, VALUBusy 87%,
// occ 72% at 4 queries/wave -- VALU-bound on per-candidate overhead (load+addr+loop),
// amortized over 4 queries. 8 queries/wave halves that overhead per query and halves
// L2 candidate traffic. Per-lane candidate mapping {id=(i<<6)+lane} and pd formula
// unchanged => identical KNN sets. Register estimate ~44-56, fits the (512,4) 64-VGPR
// budget (decisive counter: WRITE_SIZE ~2MB clean vs >50MB spill).
// Threshold: FULL-SAMPLE pass 1; L = 16th-largest lane max (bitonic) => survivors
// {v>=L} contain the exact top-16, S>=16 guaranteed, E[S]~18. Pass 2: append survivor
// (value,index) via wave-private LDS atomic. Rank phase: rank-count under
// (value desc, index asc); ranks 0..15 emit == exact lax.top_k order.
// S>64 (prob ~0) -> exhaustive rescan from L2 (always correct).
__global__ __launch_bounds__(512, 4) void knn_kernel(const float4* __restrict__ xyzw, int* __restrict__ idxout)
{
    __shared__ float  dv[8][8][64];         // 16384 B
    __shared__ unsigned short di[8][8][64]; // 8192 B
    __shared__ int cnt[8][8];               // 256 B
    const int wave = threadIdx.x >> 6;
    const int lane = threadIdx.x & 63;
    const int rbase = blockIdx.x * 64 + wave * 8;     // 64 rows/block, one batch per block
    const float4* xb = xyzw + (size_t)(rbase >> 12) * Nn;
    const int n0 = rbase & (Nn - 1);

    float4 Qu[8];
#pragma unroll
    for (int q = 0; q < 8; ++q) {
        const float4 t = xb[n0 + q];
        Qu[q] = make_float4(0.5f * t.x, 0.5f * t.y, 0.5f * t.z, t.w);   // unscale: exact
    }
    if (lane < 8) cnt[wave][lane] = 0;

    // ---- pass 1: per-lane max of exact pd over all 4096 candidates (from L2) ----
    float m[8];
#pragma unroll
    for (int q = 0; q < 8; ++q) m[q] = -3.0e38f;
    for (int i = 0; i < 64; ++i) {
        const float4 P = xb[(i << 6) + lane];
#pragma unroll
        for (int q = 0; q < 8; ++q) m[q] = fmaxf(m[q], pd5(Qu[q], P));
    }

    // ---- bitonic sort (desc) of lane maxima, 8 queries interleaved; L = rank-15 ----
#pragma unroll
    for (int k = 2; k <= 64; k <<= 1) {
#pragma unroll
        for (int j = k >> 1; j > 0; j >>= 1) {
            const bool takeMax = ((lane & j) == 0) ^ ((lane & k) != 0);
#pragma unroll
            for (int q = 0; q < 8; ++q) {
                const float o = __shfl_xor(m[q], j);
                m[q] = takeMax ? fmaxf(m[q], o) : fminf(m[q], o);
            }
        }
    }
    float L[8];
#pragma unroll
    for (int q = 0; q < 8; ++q) L[q] = __shfl(m[q], 15);

    // ---- pass 2: exact pd from L2; append survivors (wave-private lists) ----
    for (int i = 0; i < 64; ++i) {
        const float4 P = xb[(i << 6) + lane];
        const int id = (i << 6) + lane;
#pragma unroll
        for (int q = 0; q < 8; ++q) {
            const float v = pd5(Qu[q], P);
            if (v >= L[q]) {
                const int pos = atomicAdd(&cnt[wave][q], 1);
                if (pos < 64) { dv[wave][q][pos] = v; di[wave][q][pos] = (unsigned short)id; }
            }
        }
    }

    // ---- rank-count selection + output ----
#pragma unroll
    for (int q = 0; q < 8; ++q) {
        const int S = cnt[wave][q];
        if (S <= 64) {   // S >= 16 guaranteed by construction (full-sample L)
            const float myv = dv[wave][q][lane];   // lanes >= S: garbage, writes guarded
            const int   myi = di[wave][q][lane];
            int rank = 0;
            for (int i = 0; i < S; ++i) {
                const float ov = dv[wave][q][i];   // broadcast reads
                const int   oi = di[wave][q][i];
                rank += ((ov > myv) || (ov == myv && oi < myi)) ? 1 : 0;
            }
            if (lane < S && rank < Kn) idxout[(size_t)(rbase + q) * Kn + rank] = myi;
        } else {
            // fallback: exhaustive iterative selection from L2 (always correct, never expected)
            float prevv = 3.0e38f; int previ = -1;
            int sel = 0;
            for (int it = 0; it < Kn; ++it) {
                float bv = -3.0e38f; int bm = 0x7FFFFFFF;
                for (int i = 0; i < 64; ++i) {
                    const float4 P = xb[(i << 6) + lane];
                    const int id = (i << 6) + lane;
                    const float v = pd5(Qu[q], P);
                    const bool after = (v < prevv) || (v == prevv && id > previ);
                    if (after && (v > bv || (v == bv && id < bm))) { bv = v; bm = id; }
                }
#pragma unroll
                for (int off = 32; off; off >>= 1) {
                    const float ov = __shfl_xor(bv, off);
                    const int   om = __shfl_xor(bm, off);
                    if (ov > bv || (ov == bv && om < bm)) { bv = ov; bm = om; }
                }
                if (lane == it) sel = bm;
                prevv = bv; previ = bm;
            }
            if (lane < Kn) idxout[(size_t)(rbase + q) * Kn + lane] = sel;
        }
    }
}

// ---------------- Kernel B0: M = Wq^T @ Wk, v = bq @ Wk ----------------
__global__ __launch_bounds__(128) void prep_kernel(const float* __restrict__ Wq, const float* __restrict__ bq,
                                                   const float* __restrict__ Wk, const float* __restrict__ bk,
                                                   float* __restrict__ M, float* __restrict__ v)
{
    const int dp = blockIdx.x;
    const int d  = threadIdx.x;
    float acc = 0.f;
    for (int e = 0; e < Dn; ++e) acc = fmaf(Wq[e * Dn + dp], Wk[e * Dn + d], acc);
    M[dp * Dn + d] = acc;
    if (dp == 0) {
        float a = 0.f;
        for (int e = 0; e < Dn; ++e) a = fmaf(bq[e], Wk[e * Dn + d], a);
        v[d] = a;
    }
}

// ---------------- Kernel B: t16 = half(concat @ M + v)  ([32768x128] @ [128x128]) ----------------
__global__ __launch_bounds__(256) void tmat_kernel(const float* __restrict__ concat, const float* __restrict__ M,
                                                   const float* __restrict__ vvec, __half* __restrict__ t16)
{
    __shared__ float As[64][33];
    __shared__ float Ms[32][128];
    const int tid = threadIdx.x;
    const int row0 = blockIdx.x * 64;
    const int tx = tid & 15;
    const int ty = tid >> 4;
    float acc[4][8];
#pragma unroll
    for (int r = 0; r < 4; ++r)
#pragma unroll
        for (int j = 0; j < 8; ++j) acc[r][j] = 0.f;

    for (int kc = 0; kc < 4; ++kc) {
        const int k0 = kc * 32;
        __syncthreads();
#pragma unroll
        for (int p = 0; p < 8; ++p) {
            const int e = p * 256 + tid;
            const int r = e >> 5, kk = e & 31;
            As[r][kk] = concat[(size_t)(row0 + r) * Dn + k0 + kk];
        }
#pragma unroll
        for (int p = 0; p < 16; ++p) {
            const int e = p * 256 + tid;
            const int kk = e >> 7, dd = e & 127;
            Ms[kk][dd] = M[(k0 + kk) * Dn + dd];
        }
        __syncthreads();
#pragma unroll
        for (int k = 0; k < 32; ++k) {
            const float4 mA = *(const float4*)(&Ms[k][tx * 8]);
            const float4 mB = *(const float4*)(&Ms[k][tx * 8 + 4]);
            const float mj[8] = {mA.x, mA.y, mA.z, mA.w, mB.x, mB.y, mB.z, mB.w};
#pragma unroll
            for (int r = 0; r < 4; ++r) {
                const float av = As[ty * 4 + r][k];
#pragma unroll
                for (int j = 0; j < 8; ++j) acc[r][j] = fmaf(av, mj[j], acc[r][j]);
            }
        }
    }
    float vv[8];
#pragma unroll
    for (int j = 0; j < 8; ++j) vv[j] = vvec[tx * 8 + j];
#pragma unroll
    for (int r = 0; r < 4; ++r) {
        __half h[8];
#pragma unroll
        for (int j = 0; j < 8; ++j) h[j] = __float2half(acc[r][j] + vv[j]);
        *(uint4*)(&t16[(size_t)(row0 + ty * 4 + r) * Dn + tx * 8]) = *(const uint4*)h;   // 8 halves = 16B
    }
}

// ---------------- Kernel B2: c16 = half(concat), elementwise ----------------
__global__ __launch_bounds__(256) void tohalf_kernel(const float* __restrict__ in, __half* __restrict__ out)
{
    const int i = (blockIdx.x * 256 + threadIdx.x) * 4;   // 4.19M elements / 4
    const float4 v = *(const float4*)(in + i);
    __half h[4] = {__float2half(v.x), __float2half(v.y), __float2half(v.z), __float2half(v.w)};
    *(uint2*)(out + i) = *(const uint2*)h;
}

// ---------------- Kernel C: transpose fp4_features [B,C,N] -> featT16 [B,N,C] (half) ----------------
__global__ __launch_bounds__(256) void transpose_kernel(const float* __restrict__ feat, __half* __restrict__ featT16)
{
    __shared__ float tile[32][33];
    const int n0 = blockIdx.x * 32;
    const int c0 = blockIdx.y * 32;
    const int b  = blockIdx.z;
    const int ln = threadIdx.x & 31, lg = threadIdx.x >> 5;
    const float* fb = feat + (size_t)b * Cn * Nn;
#pragma unroll
    for (int p = 0; p < 4; ++p) {
        const int c = lg + p * 8;
        tile[c][ln] = fb[(size_t)(c0 + c) * Nn + n0 + ln];
    }
    __syncthreads();
    __half* ob = featT16 + (size_t)b * Nn * Cn;
#pragma unroll
    for (int p = 0; p < 4; ++p) {
        const int nn = lg + p * 8;
        ob[(size_t)(n0 + nn) * Cn + c0 + ln] = __float2half(tile[ln][nn]);
    }
}

// ---------------- Kernel D: fused scores + softmax + aggregation; fp16 operands, XCD swizzle ----------------
// Per-XCD gather working set featT16 2MB + c16 1MB + t16 1MB + knn 0.25MB ~ 4.25MB ~ L2.
// All accumulation fp32. outs padded to 260 (2-way bank aliasing = free).
__global__ __launch_bounds__(256) void fused_kernel(const __half* __restrict__ c16, const __half* __restrict__ t16,
                                                    const __half* __restrict__ featT16, const int* __restrict__ knn,
                                                    float* __restrict__ out)
{
    __shared__ float outs[16][260];
    const int wave = threadIdx.x >> 6;
    const int lane = threadIdx.x & 63;
    const int j    = lane & 15;         // neighbor task
    const int sseg = lane >> 4;         // d-segment: d in [sseg*32, sseg*32+32)
    const int swz  = (blockIdx.x & 7) * 256 + (blockIdx.x >> 3);   // XCD-chunked remap
    const int rbase = swz * 16;
    const float scale = 0.08838834764831845f;  // 1/sqrt(128)

    for (int pt = 0; pt < 4; ++pt) {
        const int row = rbase + wave * 4 + pt;
        const int b = row >> 12;
        const int ij = knn[row * Kn + j];
        const __half* trow = t16 + (size_t)row * Dn + sseg * 32;
        const __half* cj   = c16 + ((size_t)(b << 12) + ij) * Dn + sseg * 32;

        float p = 0.f;
#pragma unroll
        for (int m = 0; m < 4; ++m) {
            const uint4 tv = *(const uint4*)(trow + m * 8);
            const uint4 cv = *(const uint4*)(cj + m * 8);
            const __half2* th = (const __half2*)&tv;
            const __half2* ch = (const __half2*)&cv;
#pragma unroll
            for (int e = 0; e < 4; ++e) {
                const float2 tf = __half22float2(th[e]);
                const float2 cf = __half22float2(ch[e]);
                p = fmaf(tf.x, cf.x, p);
                p = fmaf(tf.y, cf.y, p);
            }
        }
        p += __shfl_xor(p, 16);
        p += __shfl_xor(p, 32);          // all 4 copies of task j hold t.c_j
        p *= scale;

        float mx = p;
#pragma unroll
        for (int off = 1; off <= 8; off <<= 1) mx = fmaxf(mx, __shfl_xor(mx, off));
        const float e = __expf(p - mx);
        float sum = e;
#pragma unroll
        for (int off = 1; off <= 8; off <<= 1) sum += __shfl_xor(sum, off);
        const float a = e / sum;          // this lane's neighbor-j attention

        float4 oacc = make_float4(0.f, 0.f, 0.f, 0.f);
#pragma unroll
        for (int jj = 0; jj < 16; ++jj) {
            const float aj = __shfl(a, jj);
            const int   xj = __shfl(ij, jj);
            const uint2 fv = *(const uint2*)(featT16 + ((size_t)(b << 12) + xj) * Cn + lane * 4);
            const __half2* fh = (const __half2*)&fv;
            const float2 f0 = __half22float2(fh[0]);
            const float2 f1 = __half22float2(fh[1]);
            oacc.x = fmaf(aj, f0.x, oacc.x);
            oacc.y = fmaf(aj, f0.y, oacc.y);
            oacc.z = fmaf(aj, f1.x, oacc.z);
            oacc.w = fmaf(aj, f1.y, oacc.w);
        }
        *(float4*)(&outs[wave * 4 + pt][lane * 4]) = oacc;
    }
    __syncthreads();

    const int b = rbase >> 12;
    const int n0 = rbase & (Nn - 1);
#pragma unroll
    for (int p2 = 0; p2 < 16; ++p2) {
        const int c  = (threadIdx.x >> 4) + p2 * 16;
        const int nn = threadIdx.x & 15;
        out[((size_t)b * Cn + c) * Nn + n0 + nn] = outs[nn][c];
    }
}

extern "C" void kernel_launch(void* const* d_in, const int* in_sizes, int n_in,
                              void* d_out, int out_size, void* d_ws, size_t ws_size,
                              hipStream_t stream) {
    const float* xyz    = (const float*)d_in[0];   // [B,N,3]
    const float* feat   = (const float*)d_in[1];   // [B,C,N]
    const float* concat = (const float*)d_in[2];   // [B,N,D]
    const float* Wq     = (const float*)d_in[3];
    const float* bq     = (const float*)d_in[4];
    const float* Wk     = (const float*)d_in[5];
    const float* bk     = (const float*)d_in[6];
    float* out = (float*)d_out;
    float* ws  = (float*)d_ws;

    // workspace layout (float units), offsets 16B-aligned
    float*  M       = ws;                       // 16384
    float*  v       = ws + 16512;               // 128
    int*    idx     = (int*)(ws + 16704);       // 32768*16 ints -> 524288
    __half* t16     = (__half*)(ws + 540992);   // 4,194,304 halves
    __half* c16     = (__half*)(ws + 2638144);  // 4,194,304 halves
    __half* featT16 = (__half*)(ws + 4735296);  // 8,388,608 halves
    float4* xyzw    = (float4*)(ws + 8929600);  // 32768 float4
    // total ~9.06M floats = 36.2 MB

    hipLaunchKernelGGL(pack_kernel,      dim3(128),        dim3(256), 0, stream, xyz, xyzw);
    hipLaunchKernelGGL(prep_kernel,      dim3(128),        dim3(128), 0, stream, Wq, bq, Wk, bk, M, v);
    hipLaunchKernelGGL(knn_kernel,       dim3(512),        dim3(512), 0, stream, xyzw, idx);
    hipLaunchKernelGGL(tmat_kernel,      dim3(512),        dim3(256), 0, stream, concat, M, v, t16);
    hipLaunchKernelGGL(tohalf_kernel,    dim3(4096),       dim3(256), 0, stream, concat, c16);
    hipLaunchKernelGGL(transpose_kernel, dim3(128, 8, 8),  dim3(256), 0, stream, feat, featT16);
    hipLaunchKernelGGL(fused_kernel,     dim3(2048),       dim3(256), 0, stream, c16, t16, featT16, idx, out);
}

// Round 23
// 146.555 us; speedup vs baseline: 1.1075x; 1.1075x over previous
//
#include <hip/hip_runtime.h>
#include <hip/hip_fp16.h>
#include <stdint.h>

constexpr int Bn = 8, Nn = 4096, Dn = 128, Cn = 256, Kn = 16;

// ---------------- Kernel A0: pack xyz -> float4 (2x, 2y, 2z, -xx) ----------------
// xx = ((x*x)+(y*y))+(z*z) with the reference rounding; 2x/2y/2z are exact (x2).
__global__ __launch_bounds__(256) void pack_kernel(const float* __restrict__ xyz, float4* __restrict__ xyzw)
{
    const int p = blockIdx.x * 256 + threadIdx.x;   // 32768 points
    const float x = xyz[p * 3 + 0], y = xyz[p * 3 + 1], z = xyz[p * 3 + 2];
    const float xx = __fadd_rn(__fadd_rn(__fmul_rn(x, x), __fmul_rn(y, y)), __fmul_rn(z, z));
    xyzw[p] = make_float4(2.0f * x, 2.0f * y, 2.0f * z, -xx);
}

// exact pd in 5 ops (reference-matching formula of rounds 3-22)
__device__ __forceinline__ float pd5(const float4 Qu, const float4 P)
{
    const float inner2 = __builtin_fmaf(Qu.z, P.z, __builtin_fmaf(Qu.y, P.y, __fmul_rn(Qu.x, P.x)));
    return __fadd_rn(__fadd_rn(Qu.w, inner2), P.w);
}

// ---------------- Kernel A: exact KNN, L2-direct, 4 queries/wave (r21 champion: 67us) ----------------
// 512 threads = 8 waves x 4 queries = 32 rows/block; 1024 blocks. Candidates stream from
// L2 (xyzw = 512KB, resident in every XCD L2). Profile: VGPR=24, occ 72%, VALUBusy 87%.
// r22 proved 8 queries/wave is WORSE (79us): halved wave count kills latency hiding.
// Threshold: FULL-SAMPLE pass 1; L = 16th-largest lane max (bitonic) => survivors
// {v>=L} contain the exact top-16, S>=16 guaranteed, E[S]~18. Pass 2: append survivor
// (value,index) via wave-private LDS atomic. Rank phase: rank-count under
// (value desc, index asc); ranks 0..15 emit == exact lax.top_k order.
// S>64 (prob ~0) -> exhaustive rescan from L2 (always correct).
__global__ __launch_bounds__(512, 4) void knn_kernel(const float4* __restrict__ xyzw, int* __restrict__ idxout)
{
    __shared__ float  dv[8][4][64];         // 8192 B
    __shared__ unsigned short di[8][4][64]; // 4096 B
    __shared__ int cnt[8][4];               // 128 B
    const int wave = threadIdx.x >> 6;
    const int lane = threadIdx.x & 63;
    const int rbase = blockIdx.x * 32 + wave * 4;     // 32 rows/block, one batch per block
    const float4* xb = xyzw + (size_t)(rbase >> 12) * Nn;
    const int n0 = rbase & (Nn - 1);

    float4 Qu[4];
#pragma unroll
    for (int q = 0; q < 4; ++q) {
        const float4 t = xb[n0 + q];
        Qu[q] = make_float4(0.5f * t.x, 0.5f * t.y, 0.5f * t.z, t.w);   // unscale: exact
    }
    if (lane < 4) cnt[wave][lane] = 0;

    // ---- pass 1: per-lane max of exact pd over all 4096 candidates (from L2) ----
    float m[4];
#pragma unroll
    for (int q = 0; q < 4; ++q) m[q] = -3.0e38f;
#pragma unroll 2
    for (int i = 0; i < 64; ++i) {
        const float4 P = xb[(i << 6) + lane];
#pragma unroll
        for (int q = 0; q < 4; ++q) m[q] = fmaxf(m[q], pd5(Qu[q], P));
    }

    // ---- bitonic sort (desc) of lane maxima; L = rank-15 ----
#pragma unroll
    for (int k = 2; k <= 64; k <<= 1) {
#pragma unroll
        for (int j = k >> 1; j > 0; j >>= 1) {
            const bool takeMax = ((lane & j) == 0) ^ ((lane & k) != 0);
#pragma unroll
            for (int q = 0; q < 4; ++q) {
                const float o = __shfl_xor(m[q], j);
                m[q] = takeMax ? fmaxf(m[q], o) : fminf(m[q], o);
            }
        }
    }
    float L[4];
#pragma unroll
    for (int q = 0; q < 4; ++q) L[q] = __shfl(m[q], 15);

    // ---- pass 2: exact pd from L2; append survivors (wave-private lists) ----
#pragma unroll 2
    for (int i = 0; i < 64; ++i) {
        const float4 P = xb[(i << 6) + lane];
        const int id = (i << 6) + lane;
#pragma unroll
        for (int q = 0; q < 4; ++q) {
            const float v = pd5(Qu[q], P);
            if (v >= L[q]) {
                const int pos = atomicAdd(&cnt[wave][q], 1);
                if (pos < 64) { dv[wave][q][pos] = v; di[wave][q][pos] = (unsigned short)id; }
            }
        }
    }

    // ---- rank-count selection + output ----
#pragma unroll
    for (int q = 0; q < 4; ++q) {
        const int S = cnt[wave][q];
        if (S <= 64) {   // S >= 16 guaranteed by construction (full-sample L)
            const float myv = dv[wave][q][lane];
            const int   myi = di[wave][q][lane];
            int rank = 0;
            for (int i = 0; i < S; ++i) {
                const float ov = dv[wave][q][i];
                const int   oi = di[wave][q][i];
                rank += ((ov > myv) || (ov == myv && oi < myi)) ? 1 : 0;
            }
            if (lane < S && rank < Kn) idxout[(size_t)(rbase + q) * Kn + rank] = myi;
        } else {
            float prevv = 3.0e38f; int previ = -1;
            int sel = 0;
            for (int it = 0; it < Kn; ++it) {
                float bv = -3.0e38f; int bm = 0x7FFFFFFF;
                for (int i = 0; i < 64; ++i) {
                    const float4 P = xb[(i << 6) + lane];
                    const int id = (i << 6) + lane;
                    const float v = pd5(Qu[q], P);
                    const bool after = (v < prevv) || (v == prevv && id > previ);
                    if (after && (v > bv || (v == bv && id < bm))) { bv = v; bm = id; }
                }
#pragma unroll
                for (int off = 32; off; off >>= 1) {
                    const float ov = __shfl_xor(bv, off);
                    const int   om = __shfl_xor(bm, off);
                    if (ov > bv || (ov == bv && om < bm)) { bv = ov; bm = om; }
                }
                if (lane == it) sel = bm;
                prevv = bv; previ = bm;
            }
            if (lane < Kn) idxout[(size_t)(rbase + q) * Kn + lane] = sel;
        }
    }
}

// ---------------- Kernel B0: M = Wq^T @ Wk, v = bq @ Wk ----------------
__global__ __launch_bounds__(128) void prep_kernel(const float* __restrict__ Wq, const float* __restrict__ bq,
                                                   const float* __restrict__ Wk, const float* __restrict__ bk,
                                                   float* __restrict__ M, float* __restrict__ v)
{
    const int dp = blockIdx.x;
    const int d  = threadIdx.x;
    float acc = 0.f;
    for (int e = 0; e < Dn; ++e) acc = fmaf(Wq[e * Dn + dp], Wk[e * Dn + d], acc);
    M[dp * Dn + d] = acc;
    if (dp == 0) {
        float a = 0.f;
        for (int e = 0; e < Dn; ++e) a = fmaf(bq[e], Wk[e * Dn + d], a);
        v[d] = a;
    }
}

// ---------------- Kernel B: t16 = half(concat @ M + v); also emits c16 = half(concat) ----------------
// The As staging pass touches every concat element exactly once per block -> write the
// half conversion inline (bit-identical to the old tohalf kernel), deleting one 16MB-read
// dispatch from the pipeline.
__global__ __launch_bounds__(256) void tmat_kernel(const float* __restrict__ concat, const float* __restrict__ M,
                                                   const float* __restrict__ vvec, __half* __restrict__ t16,
                                                   __half* __restrict__ c16)
{
    __shared__ float As[64][33];
    __shared__ float Ms[32][128];
    const int tid = threadIdx.x;
    const int row0 = blockIdx.x * 64;
    const int tx = tid & 15;
    const int ty = tid >> 4;
    float acc[4][8];
#pragma unroll
    for (int r = 0; r < 4; ++r)
#pragma unroll
        for (int j = 0; j < 8; ++j) acc[r][j] = 0.f;

    for (int kc = 0; kc < 4; ++kc) {
        const int k0 = kc * 32;
        __syncthreads();
#pragma unroll
        for (int p = 0; p < 8; ++p) {
            const int e = p * 256 + tid;
            const int r = e >> 5, kk = e & 31;
            const float val = concat[(size_t)(row0 + r) * Dn + k0 + kk];
            As[r][kk] = val;
            c16[(size_t)(row0 + r) * Dn + k0 + kk] = __float2half(val);
        }
#pragma unroll
        for (int p = 0; p < 16; ++p) {
            const int e = p * 256 + tid;
            const int kk = e >> 7, dd = e & 127;
            Ms[kk][dd] = M[(k0 + kk) * Dn + dd];
        }
        __syncthreads();
#pragma unroll
        for (int k = 0; k < 32; ++k) {
            const float4 mA = *(const float4*)(&Ms[k][tx * 8]);
            const float4 mB = *(const float4*)(&Ms[k][tx * 8 + 4]);
            const float mj[8] = {mA.x, mA.y, mA.z, mA.w, mB.x, mB.y, mB.z, mB.w};
#pragma unroll
            for (int r = 0; r < 4; ++r) {
                const float av = As[ty * 4 + r][k];
#pragma unroll
                for (int j = 0; j < 8; ++j) acc[r][j] = fmaf(av, mj[j], acc[r][j]);
            }
        }
    }
    float vv[8];
#pragma unroll
    for (int j = 0; j < 8; ++j) vv[j] = vvec[tx * 8 + j];
#pragma unroll
    for (int r = 0; r < 4; ++r) {
        __half h[8];
#pragma unroll
        for (int j = 0; j < 8; ++j) h[j] = __float2half(acc[r][j] + vv[j]);
        *(uint4*)(&t16[(size_t)(row0 + ty * 4 + r) * Dn + tx * 8]) = *(const uint4*)h;   // 8 halves = 16B
    }
}

// ---------------- Kernel C: transpose fp4_features [B,C,N] -> featT16 [B,N,C] (half) ----------------
__global__ __launch_bounds__(256) void transpose_kernel(const float* __restrict__ feat, __half* __restrict__ featT16)
{
    __shared__ float tile[32][33];
    const int n0 = blockIdx.x * 32;
    const int c0 = blockIdx.y * 32;
    const int b  = blockIdx.z;
    const int ln = threadIdx.x & 31, lg = threadIdx.x >> 5;
    const float* fb = feat + (size_t)b * Cn * Nn;
#pragma unroll
    for (int p = 0; p < 4; ++p) {
        const int c = lg + p * 8;
        tile[c][ln] = fb[(size_t)(c0 + c) * Nn + n0 + ln];
    }
    __syncthreads();
    __half* ob = featT16 + (size_t)b * Nn * Cn;
#pragma unroll
    for (int p = 0; p < 4; ++p) {
        const int nn = lg + p * 8;
        ob[(size_t)(n0 + nn) * Cn + c0 + ln] = __float2half(tile[ln][nn]);
    }
}

// ---------------- Kernel D: fused scores + softmax + aggregation; fp16 operands, XCD swizzle ----------------
// Per-XCD gather working set featT16 2MB + c16 1MB + t16 1MB + knn 0.25MB ~ 4.25MB ~ L2.
// All accumulation fp32. outs padded to 260 (2-way bank aliasing = free).
__global__ __launch_bounds__(256) void fused_kernel(const __half* __restrict__ c16, const __half* __restrict__ t16,
                                                    const __half* __restrict__ featT16, const int* __restrict__ knn,
                                                    float* __restrict__ out)
{
    __shared__ float outs[16][260];
    const int wave = threadIdx.x >> 6;
    const int lane = threadIdx.x & 63;
    const int j    = lane & 15;         // neighbor task
    const int sseg = lane >> 4;         // d-segment: d in [sseg*32, sseg*32+32)
    const int swz  = (blockIdx.x & 7) * 256 + (blockIdx.x >> 3);   // XCD-chunked remap
    const int rbase = swz * 16;
    const float scale = 0.08838834764831845f;  // 1/sqrt(128)

    for (int pt = 0; pt < 4; ++pt) {
        const int row = rbase + wave * 4 + pt;
        const int b = row >> 12;
        const int ij = knn[row * Kn + j];
        const __half* trow = t16 + (size_t)row * Dn + sseg * 32;
        const __half* cj   = c16 + ((size_t)(b << 12) + ij) * Dn + sseg * 32;

        float p = 0.f;
#pragma unroll
        for (int m = 0; m < 4; ++m) {
            const uint4 tv = *(const uint4*)(trow + m * 8);
            const uint4 cv = *(const uint4*)(cj + m * 8);
            const __half2* th = (const __half2*)&tv;
            const __half2* ch = (const __half2*)&cv;
#pragma unroll
            for (int e = 0; e < 4; ++e) {
                const float2 tf = __half22float2(th[e]);
                const float2 cf = __half22float2(ch[e]);
                p = fmaf(tf.x, cf.x, p);
                p = fmaf(tf.y, cf.y, p);
            }
        }
        p += __shfl_xor(p, 16);
        p += __shfl_xor(p, 32);          // all 4 copies of task j hold t.c_j
        p *= scale;

        float mx = p;
#pragma unroll
        for (int off = 1; off <= 8; off <<= 1) mx = fmaxf(mx, __shfl_xor(mx, off));
        const float e = __expf(p - mx);
        float sum = e;
#pragma unroll
        for (int off = 1; off <= 8; off <<= 1) sum += __shfl_xor(sum, off);
        const float a = e / sum;          // this lane's neighbor-j attention

        float4 oacc = make_float4(0.f, 0.f, 0.f, 0.f);
#pragma unroll
        for (int jj = 0; jj < 16; ++jj) {
            const float aj = __shfl(a, jj);
            const int   xj = __shfl(ij, jj);
            const uint2 fv = *(const uint2*)(featT16 + ((size_t)(b << 12) + xj) * Cn + lane * 4);
            const __half2* fh = (const __half2*)&fv;
            const float2 f0 = __half22float2(fh[0]);
            const float2 f1 = __half22float2(fh[1]);
            oacc.x = fmaf(aj, f0.x, oacc.x);
            oacc.y = fmaf(aj, f0.y, oacc.y);
            oacc.z = fmaf(aj, f1.x, oacc.z);
            oacc.w = fmaf(aj, f1.y, oacc.w);
        }
        *(float4*)(&outs[wave * 4 + pt][lane * 4]) = oacc;
    }
    __syncthreads();

    const int b = rbase >> 12;
    const int n0 = rbase & (Nn - 1);
#pragma unroll
    for (int p2 = 0; p2 < 16; ++p2) {
        const int c  = (threadIdx.x >> 4) + p2 * 16;
        const int nn = threadIdx.x & 15;
        out[((size_t)b * Cn + c) * Nn + n0 + nn] = outs[nn][c];
    }
}

extern "C" void kernel_launch(void* const* d_in, const int* in_sizes, int n_in,
                              void* d_out, int out_size, void* d_ws, size_t ws_size,
                              hipStream_t stream) {
    const float* xyz    = (const float*)d_in[0];   // [B,N,3]
    const float* feat   = (const float*)d_in[1];   // [B,C,N]
    const float* concat = (const float*)d_in[2];   // [B,N,D]
    const float* Wq     = (const float*)d_in[3];
    const float* bq     = (const float*)d_in[4];
    const float* Wk     = (const float*)d_in[5];
    const float* bk     = (const float*)d_in[6];
    float* out = (float*)d_out;
    float* ws  = (float*)d_ws;

    // workspace layout (float units), offsets 16B-aligned
    float*  M       = ws;                       // 16384
    float*  v       = ws + 16512;               // 128
    int*    idx     = (int*)(ws + 16704);       // 32768*16 ints -> 524288
    __half* t16     = (__half*)(ws + 540992);   // 4,194,304 halves
    __half* c16     = (__half*)(ws + 2638144);  // 4,194,304 halves
    __half* featT16 = (__half*)(ws + 4735296);  // 8,388,608 halves
    float4* xyzw    = (float4*)(ws + 8929600);  // 32768 float4
    // total ~9.06M floats = 36.2 MB

    hipLaunchKernelGGL(pack_kernel,      dim3(128),        dim3(256), 0, stream, xyz, xyzw);
    hipLaunchKernelGGL(prep_kernel,      dim3(128),        dim3(128), 0, stream, Wq, bq, Wk, bk, M, v);
    hipLaunchKernelGGL(knn_kernel,       dim3(1024),       dim3(512), 0, stream, xyzw, idx);
    hipLaunchKernelGGL(tmat_kernel,      dim3(512),        dim3(256), 0, stream, concat, M, v, t16, c16);
    hipLaunchKernelGGL(transpose_kernel, dim3(128, 8, 8),  dim3(256), 0, stream, feat, featT16);
    hipLaunchKernelGGL(fused_kernel,     dim3(2048),       dim3(256), 0, stream, c16, t16, featT16, idx, out);
}

// Round 24
// 145.828 us; speedup vs baseline: 1.1130x; 1.0050x over previous
//
#include <hip/hip_runtime.h>
#include <hip/hip_fp16.h>
#include <stdint.h>

constexpr int Bn = 8, Nn = 4096, Dn = 128, Cn = 256, Kn = 16;

// ---------------- Kernel A0: pack xyz -> float4 (2x, 2y, 2z, -xx) ----------------
// xx = ((x*x)+(y*y))+(z*z) with the reference rounding; 2x/2y/2z are exact (x2).
__global__ __launch_bounds__(256) void pack_kernel(const float* __restrict__ xyz, float4* __restrict__ xyzw)
{
    const int p = blockIdx.x * 256 + threadIdx.x;   // 32768 points
    const float x = xyz[p * 3 + 0], y = xyz[p * 3 + 1], z = xyz[p * 3 + 2];
    const float xx = __fadd_rn(__fadd_rn(__fmul_rn(x, x), __fmul_rn(y, y)), __fmul_rn(z, z));
    xyzw[p] = make_float4(2.0f * x, 2.0f * y, 2.0f * z, -xx);
}

// exact pd in 5 ops (reference-matching formula of rounds 3-23)
__device__ __forceinline__ float pd5(const float4 Qu, const float4 P)
{
    const float inner2 = __builtin_fmaf(Qu.z, P.z, __builtin_fmaf(Qu.y, P.y, __fmul_rn(Qu.x, P.x)));
    return __fadd_rn(__fadd_rn(Qu.w, inner2), P.w);
}

// ---------------- Kernel A: exact KNN, L2-direct, 4 queries/wave (r21/r23 champion: 67us) ----------------
// 512 threads = 8 waves x 4 queries = 32 rows/block; 1024 blocks. Candidates stream from
// L2 (xyzw = 512KB, resident in every XCD L2). Profile: VGPR=24, occ 72%, VALUBusy 87%.
// r22 proved 8 queries/wave is WORSE (79us): halved wave count kills latency hiding.
// Threshold: FULL-SAMPLE pass 1; L = 16th-largest lane max (bitonic) => survivors
// {v>=L} contain the exact top-16, S>=16 guaranteed, E[S]~18. Pass 2: append survivor
// (value,index) via wave-private LDS atomic. Rank phase: rank-count under
// (value desc, index asc); ranks 0..15 emit == exact lax.top_k order.
// S>64 (prob ~0) -> exhaustive rescan from L2 (always correct).
__global__ __launch_bounds__(512, 4) void knn_kernel(const float4* __restrict__ xyzw, int* __restrict__ idxout)
{
    __shared__ float  dv[8][4][64];         // 8192 B
    __shared__ unsigned short di[8][4][64]; // 4096 B
    __shared__ int cnt[8][4];               // 128 B
    const int wave = threadIdx.x >> 6;
    const int lane = threadIdx.x & 63;
    const int rbase = blockIdx.x * 32 + wave * 4;     // 32 rows/block, one batch per block
    const float4* xb = xyzw + (size_t)(rbase >> 12) * Nn;
    const int n0 = rbase & (Nn - 1);

    float4 Qu[4];
#pragma unroll
    for (int q = 0; q < 4; ++q) {
        const float4 t = xb[n0 + q];
        Qu[q] = make_float4(0.5f * t.x, 0.5f * t.y, 0.5f * t.z, t.w);   // unscale: exact
    }
    if (lane < 4) cnt[wave][lane] = 0;

    // ---- pass 1: per-lane max of exact pd over all 4096 candidates (from L2) ----
    float m[4];
#pragma unroll
    for (int q = 0; q < 4; ++q) m[q] = -3.0e38f;
#pragma unroll 2
    for (int i = 0; i < 64; ++i) {
        const float4 P = xb[(i << 6) + lane];
#pragma unroll
        for (int q = 0; q < 4; ++q) m[q] = fmaxf(m[q], pd5(Qu[q], P));
    }

    // ---- bitonic sort (desc) of lane maxima; L = rank-15 ----
#pragma unroll
    for (int k = 2; k <= 64; k <<= 1) {
#pragma unroll
        for (int j = k >> 1; j > 0; j >>= 1) {
            const bool takeMax = ((lane & j) == 0) ^ ((lane & k) != 0);
#pragma unroll
            for (int q = 0; q < 4; ++q) {
                const float o = __shfl_xor(m[q], j);
                m[q] = takeMax ? fmaxf(m[q], o) : fminf(m[q], o);
            }
        }
    }
    float L[4];
#pragma unroll
    for (int q = 0; q < 4; ++q) L[q] = __shfl(m[q], 15);

    // ---- pass 2: exact pd from L2; append survivors (wave-private lists) ----
#pragma unroll 2
    for (int i = 0; i < 64; ++i) {
        const float4 P = xb[(i << 6) + lane];
        const int id = (i << 6) + lane;
#pragma unroll
        for (int q = 0; q < 4; ++q) {
            const float v = pd5(Qu[q], P);
            if (v >= L[q]) {
                const int pos = atomicAdd(&cnt[wave][q], 1);
                if (pos < 64) { dv[wave][q][pos] = v; di[wave][q][pos] = (unsigned short)id; }
            }
        }
    }

    // ---- rank-count selection + output ----
#pragma unroll
    for (int q = 0; q < 4; ++q) {
        const int S = cnt[wave][q];
        if (S <= 64) {   // S >= 16 guaranteed by construction (full-sample L)
            const float myv = dv[wave][q][lane];
            const int   myi = di[wave][q][lane];
            int rank = 0;
            for (int i = 0; i < S; ++i) {
                const float ov = dv[wave][q][i];
                const int   oi = di[wave][q][i];
                rank += ((ov > myv) || (ov == myv && oi < myi)) ? 1 : 0;
            }
            if (lane < S && rank < Kn) idxout[(size_t)(rbase + q) * Kn + rank] = myi;
        } else {
            float prevv = 3.0e38f; int previ = -1;
            int sel = 0;
            for (int it = 0; it < Kn; ++it) {
                float bv = -3.0e38f; int bm = 0x7FFFFFFF;
                for (int i = 0; i < 64; ++i) {
                    const float4 P = xb[(i << 6) + lane];
                    const int id = (i << 6) + lane;
                    const float v = pd5(Qu[q], P);
                    const bool after = (v < prevv) || (v == prevv && id > previ);
                    if (after && (v > bv || (v == bv && id < bm))) { bv = v; bm = id; }
                }
#pragma unroll
                for (int off = 32; off; off >>= 1) {
                    const float ov = __shfl_xor(bv, off);
                    const int   om = __shfl_xor(bm, off);
                    if (ov > bv || (ov == bv && om < bm)) { bv = ov; bm = om; }
                }
                if (lane == it) sel = bm;
                prevv = bv; previ = bm;
            }
            if (lane < Kn) idxout[(size_t)(rbase + q) * Kn + lane] = sel;
        }
    }
}

// ---------------- Kernel B0: M = Wq^T @ Wk, v = bq @ Wk ----------------
__global__ __launch_bounds__(128) void prep_kernel(const float* __restrict__ Wq, const float* __restrict__ bq,
                                                   const float* __restrict__ Wk, const float* __restrict__ bk,
                                                   float* __restrict__ M, float* __restrict__ v)
{
    const int dp = blockIdx.x;
    const int d  = threadIdx.x;
    float acc = 0.f;
    for (int e = 0; e < Dn; ++e) acc = fmaf(Wq[e * Dn + dp], Wk[e * Dn + d], acc);
    M[dp * Dn + d] = acc;
    if (dp == 0) {
        float a = 0.f;
        for (int e = 0; e < Dn; ++e) a = fmaf(bq[e], Wk[e * Dn + d], a);
        v[d] = a;
    }
}

// ---------------- Kernel B: t16 = half(concat @ M + v); also emits c16 = half(concat) ----------------
__global__ __launch_bounds__(256) void tmat_kernel(const float* __restrict__ concat, const float* __restrict__ M,
                                                   const float* __restrict__ vvec, __half* __restrict__ t16,
                                                   __half* __restrict__ c16)
{
    __shared__ float As[64][33];
    __shared__ float Ms[32][128];
    const int tid = threadIdx.x;
    const int row0 = blockIdx.x * 64;
    const int tx = tid & 15;
    const int ty = tid >> 4;
    float acc[4][8];
#pragma unroll
    for (int r = 0; r < 4; ++r)
#pragma unroll
        for (int j = 0; j < 8; ++j) acc[r][j] = 0.f;

    for (int kc = 0; kc < 4; ++kc) {
        const int k0 = kc * 32;
        __syncthreads();
#pragma unroll
        for (int p = 0; p < 8; ++p) {
            const int e = p * 256 + tid;
            const int r = e >> 5, kk = e & 31;
            const float val = concat[(size_t)(row0 + r) * Dn + k0 + kk];
            As[r][kk] = val;
            c16[(size_t)(row0 + r) * Dn + k0 + kk] = __float2half(val);
        }
#pragma unroll
        for (int p = 0; p < 16; ++p) {
            const int e = p * 256 + tid;
            const int kk = e >> 7, dd = e & 127;
            Ms[kk][dd] = M[(k0 + kk) * Dn + dd];
        }
        __syncthreads();
#pragma unroll
        for (int k = 0; k < 32; ++k) {
            const float4 mA = *(const float4*)(&Ms[k][tx * 8]);
            const float4 mB = *(const float4*)(&Ms[k][tx * 8 + 4]);
            const float mj[8] = {mA.x, mA.y, mA.z, mA.w, mB.x, mB.y, mB.z, mB.w};
#pragma unroll
            for (int r = 0; r < 4; ++r) {
                const float av = As[ty * 4 + r][k];
#pragma unroll
                for (int j = 0; j < 8; ++j) acc[r][j] = fmaf(av, mj[j], acc[r][j]);
            }
        }
    }
    float vv[8];
#pragma unroll
    for (int j = 0; j < 8; ++j) vv[j] = vvec[tx * 8 + j];
#pragma unroll
    for (int r = 0; r < 4; ++r) {
        __half h[8];
#pragma unroll
        for (int j = 0; j < 8; ++j) h[j] = __float2half(acc[r][j] + vv[j]);
        *(uint4*)(&t16[(size_t)(row0 + ty * 4 + r) * Dn + tx * 8]) = *(const uint4*)h;   // 8 halves = 16B
    }
}

// ---------------- Kernel C: transpose fp4_features [B,C,N] -> featT16 [B,N,C] (half) ----------------
__global__ __launch_bounds__(256) void transpose_kernel(const float* __restrict__ feat, __half* __restrict__ featT16)
{
    __shared__ float tile[32][33];
    const int n0 = blockIdx.x * 32;
    const int c0 = blockIdx.y * 32;
    const int b  = blockIdx.z;
    const int ln = threadIdx.x & 31, lg = threadIdx.x >> 5;
    const float* fb = feat + (size_t)b * Cn * Nn;
#pragma unroll
    for (int p = 0; p < 4; ++p) {
        const int c = lg + p * 8;
        tile[c][ln] = fb[(size_t)(c0 + c) * Nn + n0 + ln];
    }
    __syncthreads();
    __half* ob = featT16 + (size_t)b * Nn * Cn;
#pragma unroll
    for (int p = 0; p < 4; ++p) {
        const int nn = lg + p * 8;
        ob[(size_t)(n0 + nn) * Cn + c0 + ln] = __float2half(tile[ln][nn]);
    }
}

// ---------------- Kernel D: fused scores + softmax + aggregation; cross-pt ILP restructure ----------------
// All 4 pts' phases interleaved: 4 independent score-dot chains, 4-way interleaved
// shuffle reduces/softmax, and a single gather loop issuing 4 pts' feature loads per jj
// (up to 64 independent L2 loads in flight vs 16). fp16 operands, fp32 accumulation,
// XCD-chunked swizzle (r17), outs padded to 260.
__global__ __launch_bounds__(256) void fused_kernel(const __half* __restrict__ c16, const __half* __restrict__ t16,
                                                    const __half* __restrict__ featT16, const int* __restrict__ knn,
                                                    float* __restrict__ out)
{
    __shared__ float outs[16][260];
    const int wave = threadIdx.x >> 6;
    const int lane = threadIdx.x & 63;
    const int j    = lane & 15;         // neighbor task
    const int sseg = lane >> 4;         // d-segment: d in [sseg*32, sseg*32+32)
    const int swz  = (blockIdx.x & 7) * 256 + (blockIdx.x >> 3);   // XCD-chunked remap
    const int rbase = swz * 16;
    const int b = rbase >> 12;          // all 16 rows of this block share one batch
    const float scale = 0.08838834764831845f;  // 1/sqrt(128)

    // ---- phase 1a: neighbor ids + score dots for all 4 pts (independent chains) ----
    int ij[4];
    float p[4];
#pragma unroll
    for (int pt = 0; pt < 4; ++pt) {
        const int row = rbase + wave * 4 + pt;
        ij[pt] = knn[row * Kn + j];
    }
#pragma unroll
    for (int pt = 0; pt < 4; ++pt) {
        const int row = rbase + wave * 4 + pt;
        const __half* trow = t16 + (size_t)row * Dn + sseg * 32;
        const __half* cj   = c16 + ((size_t)(b << 12) + ij[pt]) * Dn + sseg * 32;
        float acc = 0.f;
#pragma unroll
        for (int m = 0; m < 4; ++m) {
            const uint4 tv = *(const uint4*)(trow + m * 8);
            const uint4 cv = *(const uint4*)(cj + m * 8);
            const __half2* th = (const __half2*)&tv;
            const __half2* ch = (const __half2*)&cv;
#pragma unroll
            for (int e = 0; e < 4; ++e) {
                const float2 tf = __half22float2(th[e]);
                const float2 cf = __half22float2(ch[e]);
                acc = fmaf(tf.x, cf.x, acc);
                acc = fmaf(tf.y, cf.y, acc);
            }
        }
        p[pt] = acc;
    }

    // ---- phase 1b: cross-segment reduce + softmax, 4 pts interleaved ----
#pragma unroll
    for (int pt = 0; pt < 4; ++pt) p[pt] += __shfl_xor(p[pt], 16);
#pragma unroll
    for (int pt = 0; pt < 4; ++pt) { p[pt] += __shfl_xor(p[pt], 32); p[pt] *= scale; }

    float mx[4];
#pragma unroll
    for (int pt = 0; pt < 4; ++pt) mx[pt] = p[pt];
#pragma unroll
    for (int off = 1; off <= 8; off <<= 1)
#pragma unroll
        for (int pt = 0; pt < 4; ++pt) mx[pt] = fmaxf(mx[pt], __shfl_xor(mx[pt], off));

    float a[4], sum[4];
#pragma unroll
    for (int pt = 0; pt < 4; ++pt) { a[pt] = __expf(p[pt] - mx[pt]); sum[pt] = a[pt]; }
#pragma unroll
    for (int off = 1; off <= 8; off <<= 1)
#pragma unroll
        for (int pt = 0; pt < 4; ++pt) sum[pt] += __shfl_xor(sum[pt], off);
#pragma unroll
    for (int pt = 0; pt < 4; ++pt) a[pt] /= sum[pt];

    // ---- phase 2: feature gather, 4 pts interleaved (4x loads in flight per jj) ----
    float4 oacc[4];
#pragma unroll
    for (int pt = 0; pt < 4; ++pt) oacc[pt] = make_float4(0.f, 0.f, 0.f, 0.f);
#pragma unroll
    for (int jj = 0; jj < 16; ++jj) {
#pragma unroll
        for (int pt = 0; pt < 4; ++pt) {
            const float aj = __shfl(a[pt], jj);
            const int   xj = __shfl(ij[pt], jj);
            const uint2 fv = *(const uint2*)(featT16 + ((size_t)(b << 12) + xj) * Cn + lane * 4);
            const __half2* fh = (const __half2*)&fv;
            const float2 f0 = __half22float2(fh[0]);
            const float2 f1 = __half22float2(fh[1]);
            oacc[pt].x = fmaf(aj, f0.x, oacc[pt].x);
            oacc[pt].y = fmaf(aj, f0.y, oacc[pt].y);
            oacc[pt].z = fmaf(aj, f1.x, oacc[pt].z);
            oacc[pt].w = fmaf(aj, f1.y, oacc[pt].w);
        }
    }
#pragma unroll
    for (int pt = 0; pt < 4; ++pt)
        *(float4*)(&outs[wave * 4 + pt][lane * 4]) = oacc[pt];
    __syncthreads();

    const int n0 = rbase & (Nn - 1);
#pragma unroll
    for (int p2 = 0; p2 < 16; ++p2) {
        const int c  = (threadIdx.x >> 4) + p2 * 16;
        const int nn = threadIdx.x & 15;
        out[((size_t)b * Cn + c) * Nn + n0 + nn] = outs[nn][c];
    }
}

extern "C" void kernel_launch(void* const* d_in, const int* in_sizes, int n_in,
                              void* d_out, int out_size, void* d_ws, size_t ws_size,
                              hipStream_t stream) {
    const float* xyz    = (const float*)d_in[0];   // [B,N,3]
    const float* feat   = (const float*)d_in[1];   // [B,C,N]
    const float* concat = (const float*)d_in[2];   // [B,N,D]
    const float* Wq     = (const float*)d_in[3];
    const float* bq     = (const float*)d_in[4];
    const float* Wk     = (const float*)d_in[5];
    const float* bk     = (const float*)d_in[6];
    float* out = (float*)d_out;
    float* ws  = (float*)d_ws;

    // workspace layout (float units), offsets 16B-aligned
    float*  M       = ws;                       // 16384
    float*  v       = ws + 16512;               // 128
    int*    idx     = (int*)(ws + 16704);       // 32768*16 ints -> 524288
    __half* t16     = (__half*)(ws + 540992);   // 4,194,304 halves
    __half* c16     = (__half*)(ws + 2638144);  // 4,194,304 halves
    __half* featT16 = (__half*)(ws + 4735296);  // 8,388,608 halves
    float4* xyzw    = (float4*)(ws + 8929600);  // 32768 float4
    // total ~9.06M floats = 36.2 MB

    hipLaunchKernelGGL(pack_kernel,      dim3(128),        dim3(256), 0, stream, xyz, xyzw);
    hipLaunchKernelGGL(prep_kernel,      dim3(128),        dim3(128), 0, stream, Wq, bq, Wk, bk, M, v);
    hipLaunchKernelGGL(knn_kernel,       dim3(1024),       dim3(512), 0, stream, xyzw, idx);
    hipLaunchKernelGGL(tmat_kernel,      dim3(512),        dim3(256), 0, stream, concat, M, v, t16, c16);
    hipLaunchKernelGGL(transpose_kernel, dim3(128, 8, 8),  dim3(256), 0, stream, feat, featT16);
    hipLaunchKernelGGL(fused_kernel,     dim3(2048),       dim3(256), 0, stream, c16, t16, featT16, idx, out);
}

// Round 25
// 143.887 us; speedup vs baseline: 1.1281x; 1.0135x over previous
//
#include <hip/hip_runtime.h>
#include <hip/hip_fp16.h>
#include <stdint.h>

constexpr int Bn = 8, Nn = 4096, Dn = 128, Cn = 256, Kn = 16;

// ---------------- Kernel A0: pack xyz -> float4 (2x, 2y, 2z, -xx) ----------------
// xx = ((x*x)+(y*y))+(z*z) with the reference rounding; 2x/2y/2z are exact (x2).
__global__ __launch_bounds__(256) void pack_kernel(const float* __restrict__ xyz, float4* __restrict__ xyzw)
{
    const int p = blockIdx.x * 256 + threadIdx.x;   // 32768 points
    const float x = xyz[p * 3 + 0], y = xyz[p * 3 + 1], z = xyz[p * 3 + 2];
    const float xx = __fadd_rn(__fadd_rn(__fmul_rn(x, x), __fmul_rn(y, y)), __fmul_rn(z, z));
    xyzw[p] = make_float4(2.0f * x, 2.0f * y, 2.0f * z, -xx);
}

// exact pd in 5 ops (reference-matching formula of rounds 3-24)
__device__ __forceinline__ float pd5(const float4 Qu, const float4 P)
{
    const float inner2 = __builtin_fmaf(Qu.z, P.z, __builtin_fmaf(Qu.y, P.y, __fmul_rn(Qu.x, P.x)));
    return __fadd_rn(__fadd_rn(Qu.w, inner2), P.w);
}

// ---------------- Kernel A: exact KNN, L2-direct, 4 queries/wave (r21/r23 champion: 67us) ----------------
// 512 threads = 8 waves x 4 queries = 32 rows/block; 1024 blocks. Candidates stream from
// L2 (xyzw = 512KB, resident in every XCD L2). Profile: VGPR=24, occ 72%, VALUBusy 88%.
// Threshold: FULL-SAMPLE pass 1; L = 16th-largest lane max (bitonic) => survivors
// {v>=L} contain the exact top-16, S>=16 guaranteed, E[S]~18. Pass 2: append survivor
// (value,index) via wave-private LDS atomic. Rank phase: rank-count under
// (value desc, index asc); ranks 0..15 emit == exact lax.top_k order.
// S>64 (prob ~0) -> exhaustive rescan from L2 (always correct).
__global__ __launch_bounds__(512, 4) void knn_kernel(const float4* __restrict__ xyzw, int* __restrict__ idxout)
{
    __shared__ float  dv[8][4][64];         // 8192 B
    __shared__ unsigned short di[8][4][64]; // 4096 B
    __shared__ int cnt[8][4];               // 128 B
    const int wave = threadIdx.x >> 6;
    const int lane = threadIdx.x & 63;
    const int rbase = blockIdx.x * 32 + wave * 4;     // 32 rows/block, one batch per block
    const float4* xb = xyzw + (size_t)(rbase >> 12) * Nn;
    const int n0 = rbase & (Nn - 1);

    float4 Qu[4];
#pragma unroll
    for (int q = 0; q < 4; ++q) {
        const float4 t = xb[n0 + q];
        Qu[q] = make_float4(0.5f * t.x, 0.5f * t.y, 0.5f * t.z, t.w);   // unscale: exact
    }
    if (lane < 4) cnt[wave][lane] = 0;

    // ---- pass 1: per-lane max of exact pd over all 4096 candidates (from L2) ----
    float m[4];
#pragma unroll
    for (int q = 0; q < 4; ++q) m[q] = -3.0e38f;
#pragma unroll 2
    for (int i = 0; i < 64; ++i) {
        const float4 P = xb[(i << 6) + lane];
#pragma unroll
        for (int q = 0; q < 4; ++q) m[q] = fmaxf(m[q], pd5(Qu[q], P));
    }

    // ---- bitonic sort (desc) of lane maxima; L = rank-15 ----
#pragma unroll
    for (int k = 2; k <= 64; k <<= 1) {
#pragma unroll
        for (int j = k >> 1; j > 0; j >>= 1) {
            const bool takeMax = ((lane & j) == 0) ^ ((lane & k) != 0);
#pragma unroll
            for (int q = 0; q < 4; ++q) {
                const float o = __shfl_xor(m[q], j);
                m[q] = takeMax ? fmaxf(m[q], o) : fminf(m[q], o);
            }
        }
    }
    float L[4];
#pragma unroll
    for (int q = 0; q < 4; ++q) L[q] = __shfl(m[q], 15);

    // ---- pass 2: exact pd from L2; append survivors (wave-private lists) ----
#pragma unroll 2
    for (int i = 0; i < 64; ++i) {
        const float4 P = xb[(i << 6) + lane];
        const int id = (i << 6) + lane;
#pragma unroll
        for (int q = 0; q < 4; ++q) {
            const float v = pd5(Qu[q], P);
            if (v >= L[q]) {
                const int pos = atomicAdd(&cnt[wave][q], 1);
                if (pos < 64) { dv[wave][q][pos] = v; di[wave][q][pos] = (unsigned short)id; }
            }
        }
    }

    // ---- rank-count selection + output ----
#pragma unroll
    for (int q = 0; q < 4; ++q) {
        const int S = cnt[wave][q];
        if (S <= 64) {   // S >= 16 guaranteed by construction (full-sample L)
            const float myv = dv[wave][q][lane];
            const int   myi = di[wave][q][lane];
            int rank = 0;
            for (int i = 0; i < S; ++i) {
                const float ov = dv[wave][q][i];
                const int   oi = di[wave][q][i];
                rank += ((ov > myv) || (ov == myv && oi < myi)) ? 1 : 0;
            }
            if (lane < S && rank < Kn) idxout[(size_t)(rbase + q) * Kn + rank] = myi;
        } else {
            float prevv = 3.0e38f; int previ = -1;
            int sel = 0;
            for (int it = 0; it < Kn; ++it) {
                float bv = -3.0e38f; int bm = 0x7FFFFFFF;
                for (int i = 0; i < 64; ++i) {
                    const float4 P = xb[(i << 6) + lane];
                    const int id = (i << 6) + lane;
                    const float v = pd5(Qu[q], P);
                    const bool after = (v < prevv) || (v == prevv && id > previ);
                    if (after && (v > bv || (v == bv && id < bm))) { bv = v; bm = id; }
                }
#pragma unroll
                for (int off = 32; off; off >>= 1) {
                    const float ov = __shfl_xor(bv, off);
                    const int   om = __shfl_xor(bm, off);
                    if (ov > bv || (ov == bv && om < bm)) { bv = ov; bm = om; }
                }
                if (lane == it) sel = bm;
                prevv = bv; previ = bm;
            }
            if (lane < Kn) idxout[(size_t)(rbase + q) * Kn + lane] = sel;
        }
    }
}

// ---------------- Kernel B0: M = Wq^T @ Wk, v = bq @ Wk ----------------
__global__ __launch_bounds__(128) void prep_kernel(const float* __restrict__ Wq, const float* __restrict__ bq,
                                                   const float* __restrict__ Wk, const float* __restrict__ bk,
                                                   float* __restrict__ M, float* __restrict__ v)
{
    const int dp = blockIdx.x;
    const int d  = threadIdx.x;
    float acc = 0.f;
    for (int e = 0; e < Dn; ++e) acc = fmaf(Wq[e * Dn + dp], Wk[e * Dn + d], acc);
    M[dp * Dn + d] = acc;
    if (dp == 0) {
        float a = 0.f;
        for (int e = 0; e < Dn; ++e) a = fmaf(bq[e], Wk[e * Dn + d], a);
        v[d] = a;
    }
}

// ---------------- Kernel B: t16 = half(concat @ M + v); also emits c16 = half(concat) ----------------
__global__ __launch_bounds__(256) void tmat_kernel(const float* __restrict__ concat, const float* __restrict__ M,
                                                   const float* __restrict__ vvec, __half* __restrict__ t16,
                                                   __half* __restrict__ c16)
{
    __shared__ float As[64][33];
    __shared__ float Ms[32][128];
    const int tid = threadIdx.x;
    const int row0 = blockIdx.x * 64;
    const int tx = tid & 15;
    const int ty = tid >> 4;
    float acc[4][8];
#pragma unroll
    for (int r = 0; r < 4; ++r)
#pragma unroll
        for (int j = 0; j < 8; ++j) acc[r][j] = 0.f;

    for (int kc = 0; kc < 4; ++kc) {
        const int k0 = kc * 32;
        __syncthreads();
#pragma unroll
        for (int p = 0; p < 8; ++p) {
            const int e = p * 256 + tid;
            const int r = e >> 5, kk = e & 31;
            const float val = concat[(size_t)(row0 + r) * Dn + k0 + kk];
            As[r][kk] = val;
            c16[(size_t)(row0 + r) * Dn + k0 + kk] = __float2half(val);
        }
#pragma unroll
        for (int p = 0; p < 16; ++p) {
            const int e = p * 256 + tid;
            const int kk = e >> 7, dd = e & 127;
            Ms[kk][dd] = M[(k0 + kk) * Dn + dd];
        }
        __syncthreads();
#pragma unroll
        for (int k = 0; k < 32; ++k) {
            const float4 mA = *(const float4*)(&Ms[k][tx * 8]);
            const float4 mB = *(const float4*)(&Ms[k][tx * 8 + 4]);
            const float mj[8] = {mA.x, mA.y, mA.z, mA.w, mB.x, mB.y, mB.z, mB.w};
#pragma unroll
            for (int r = 0; r < 4; ++r) {
                const float av = As[ty * 4 + r][k];
#pragma unroll
                for (int j = 0; j < 8; ++j) acc[r][j] = fmaf(av, mj[j], acc[r][j]);
            }
        }
    }
    float vv[8];
#pragma unroll
    for (int j = 0; j < 8; ++j) vv[j] = vvec[tx * 8 + j];
#pragma unroll
    for (int r = 0; r < 4; ++r) {
        __half h[8];
#pragma unroll
        for (int j = 0; j < 8; ++j) h[j] = __float2half(acc[r][j] + vv[j]);
        *(uint4*)(&t16[(size_t)(row0 + ty * 4 + r) * Dn + tx * 8]) = *(const uint4*)h;   // 8 halves = 16B
    }
}

// ---------------- Kernel C: transpose fp4_features [B,C,N] -> featT16 [B,N,C] (half) ----------------
__global__ __launch_bounds__(256) void transpose_kernel(const float* __restrict__ feat, __half* __restrict__ featT16)
{
    __shared__ float tile[32][33];
    const int n0 = blockIdx.x * 32;
    const int c0 = blockIdx.y * 32;
    const int b  = blockIdx.z;
    const int ln = threadIdx.x & 31, lg = threadIdx.x >> 5;
    const float* fb = feat + (size_t)b * Cn * Nn;
#pragma unroll
    for (int p = 0; p < 4; ++p) {
        const int c = lg + p * 8;
        tile[c][ln] = fb[(size_t)(c0 + c) * Nn + n0 + ln];
    }
    __syncthreads();
    __half* ob = featT16 + (size_t)b * Nn * Cn;
#pragma unroll
    for (int p = 0; p < 4; ++p) {
        const int nn = lg + p * 8;
        ob[(size_t)(n0 + nn) * Cn + c0 + ln] = __float2half(tile[ln][nn]);
    }
}

// ---------------- Kernel D: fused scores + softmax + aggregation; (256,8) occupancy target ----------------
// Latency-bound gather kernel (VALUBusy 14%, occ 44% at default target). (256,8) requests
// 8 waves/EU (32/CU); VGPR cap 2048/32=64 >= current 48 -> no spill risk. Cross-pt ILP
// structure from r24 retained. fp16 operands, fp32 accumulation, XCD-chunked swizzle.
__global__ __launch_bounds__(256, 8) void fused_kernel(const __half* __restrict__ c16, const __half* __restrict__ t16,
                                                       const __half* __restrict__ featT16, const int* __restrict__ knn,
                                                       float* __restrict__ out)
{
    __shared__ float outs[16][260];
    const int wave = threadIdx.x >> 6;
    const int lane = threadIdx.x & 63;
    const int j    = lane & 15;         // neighbor task
    const int sseg = lane >> 4;         // d-segment: d in [sseg*32, sseg*32+32)
    const int swz  = (blockIdx.x & 7) * 256 + (blockIdx.x >> 3);   // XCD-chunked remap
    const int rbase = swz * 16;
    const int b = rbase >> 12;          // all 16 rows of this block share one batch
    const float scale = 0.08838834764831845f;  // 1/sqrt(128)

    // ---- phase 1a: neighbor ids + score dots for all 4 pts (independent chains) ----
    int ij[4];
    float p[4];
#pragma unroll
    for (int pt = 0; pt < 4; ++pt) {
        const int row = rbase + wave * 4 + pt;
        ij[pt] = knn[row * Kn + j];
    }
#pragma unroll
    for (int pt = 0; pt < 4; ++pt) {
        const int row = rbase + wave * 4 + pt;
        const __half* trow = t16 + (size_t)row * Dn + sseg * 32;
        const __half* cj   = c16 + ((size_t)(b << 12) + ij[pt]) * Dn + sseg * 32;
        float acc = 0.f;
#pragma unroll
        for (int m = 0; m < 4; ++m) {
            const uint4 tv = *(const uint4*)(trow + m * 8);
            const uint4 cv = *(const uint4*)(cj + m * 8);
            const __half2* th = (const __half2*)&tv;
            const __half2* ch = (const __half2*)&cv;
#pragma unroll
            for (int e = 0; e < 4; ++e) {
                const float2 tf = __half22float2(th[e]);
                const float2 cf = __half22float2(ch[e]);
                acc = fmaf(tf.x, cf.x, acc);
                acc = fmaf(tf.y, cf.y, acc);
            }
        }
        p[pt] = acc;
    }

    // ---- phase 1b: cross-segment reduce + softmax, 4 pts interleaved ----
#pragma unroll
    for (int pt = 0; pt < 4; ++pt) p[pt] += __shfl_xor(p[pt], 16);
#pragma unroll
    for (int pt = 0; pt < 4; ++pt) { p[pt] += __shfl_xor(p[pt], 32); p[pt] *= scale; }

    float mx[4];
#pragma unroll
    for (int pt = 0; pt < 4; ++pt) mx[pt] = p[pt];
#pragma unroll
    for (int off = 1; off <= 8; off <<= 1)
#pragma unroll
        for (int pt = 0; pt < 4; ++pt) mx[pt] = fmaxf(mx[pt], __shfl_xor(mx[pt], off));

    float a[4], sum[4];
#pragma unroll
    for (int pt = 0; pt < 4; ++pt) { a[pt] = __expf(p[pt] - mx[pt]); sum[pt] = a[pt]; }
#pragma unroll
    for (int off = 1; off <= 8; off <<= 1)
#pragma unroll
        for (int pt = 0; pt < 4; ++pt) sum[pt] += __shfl_xor(sum[pt], off);
#pragma unroll
    for (int pt = 0; pt < 4; ++pt) a[pt] /= sum[pt];

    // ---- phase 2: feature gather, 4 pts interleaved (4x loads in flight per jj) ----
    float4 oacc[4];
#pragma unroll
    for (int pt = 0; pt < 4; ++pt) oacc[pt] = make_float4(0.f, 0.f, 0.f, 0.f);
#pragma unroll
    for (int jj = 0; jj < 16; ++jj) {
#pragma unroll
        for (int pt = 0; pt < 4; ++pt) {
            const float aj = __shfl(a[pt], jj);
            const int   xj = __shfl(ij[pt], jj);
            const uint2 fv = *(const uint2*)(featT16 + ((size_t)(b << 12) + xj) * Cn + lane * 4);
            const __half2* fh = (const __half2*)&fv;
            const float2 f0 = __half22float2(fh[0]);
            const float2 f1 = __half22float2(fh[1]);
            oacc[pt].x = fmaf(aj, f0.x, oacc[pt].x);
            oacc[pt].y = fmaf(aj, f0.y, oacc[pt].y);
            oacc[pt].z = fmaf(aj, f1.x, oacc[pt].z);
            oacc[pt].w = fmaf(aj, f1.y, oacc[pt].w);
        }
    }
#pragma unroll
    for (int pt = 0; pt < 4; ++pt)
        *(float4*)(&outs[wave * 4 + pt][lane * 4]) = oacc[pt];
    __syncthreads();

    const int n0 = rbase & (Nn - 1);
#pragma unroll
    for (int p2 = 0; p2 < 16; ++p2) {
        const int c  = (threadIdx.x >> 4) + p2 * 16;
        const int nn = threadIdx.x & 15;
        out[((size_t)b * Cn + c) * Nn + n0 + nn] = outs[nn][c];
    }
}

extern "C" void kernel_launch(void* const* d_in, const int* in_sizes, int n_in,
                              void* d_out, int out_size, void* d_ws, size_t ws_size,
                              hipStream_t stream) {
    const float* xyz    = (const float*)d_in[0];   // [B,N,3]
    const float* feat   = (const float*)d_in[1];   // [B,C,N]
    const float* concat = (const float*)d_in[2];   // [B,N,D]
    const float* Wq     = (const float*)d_in[3];
    const float* bq     = (const float*)d_in[4];
    const float* Wk     = (const float*)d_in[5];
    const float* bk     = (const float*)d_in[6];
    float* out = (float*)d_out;
    float* ws  = (float*)d_ws;

    // workspace layout (float units), offsets 16B-aligned
    float*  M       = ws;                       // 16384
    float*  v       = ws + 16512;               // 128
    int*    idx     = (int*)(ws + 16704);       // 32768*16 ints -> 524288
    __half* t16     = (__half*)(ws + 540992);   // 4,194,304 halves
    __half* c16     = (__half*)(ws + 2638144);  // 4,194,304 halves
    __half* featT16 = (__half*)(ws + 4735296);  // 8,388,608 halves
    float4* xyzw    = (float4*)(ws + 8929600);  // 32768 float4
    // total ~9.06M floats = 36.2 MB

    hipLaunchKernelGGL(pack_kernel,      dim3(128),        dim3(256), 0, stream, xyz, xyzw);
    hipLaunchKernelGGL(prep_kernel,      dim3(128),        dim3(128), 0, stream, Wq, bq, Wk, bk, M, v);
    hipLaunchKernelGGL(knn_kernel,       dim3(1024),       dim3(512), 0, stream, xyzw, idx);
    hipLaunchKernelGGL(tmat_kernel,      dim3(512),        dim3(256), 0, stream, concat, M, v, t16, c16);
    hipLaunchKernelGGL(transpose_kernel, dim3(128, 8, 8),  dim3(256), 0, stream, feat, featT16);
    hipLaunchKernelGGL(fused_kernel,     dim3(2048),       dim3(256), 0, stream, c16, t16, featT16, idx, out);
}

// Round 26
// 143.676 us; speedup vs baseline: 1.1297x; 1.0015x over previous
//
#include <hip/hip_runtime.h>
#include <hip/hip_fp16.h>
#include <stdint.h>

constexpr int Bn = 8, Nn = 4096, Dn = 128, Cn = 256, Kn = 16;

// ---------------- Kernel A0: pack xyz -> float4 (2x, 2y, 2z, -xx) ----------------
// xx = ((x*x)+(y*y))+(z*z) with the reference rounding; 2x/2y/2z are exact (x2).
__global__ __launch_bounds__(256) void pack_kernel(const float* __restrict__ xyz, float4* __restrict__ xyzw)
{
    const int p = blockIdx.x * 256 + threadIdx.x;   // 32768 points
    const float x = xyz[p * 3 + 0], y = xyz[p * 3 + 1], z = xyz[p * 3 + 2];
    const float xx = __fadd_rn(__fadd_rn(__fmul_rn(x, x), __fmul_rn(y, y)), __fmul_rn(z, z));
    xyzw[p] = make_float4(2.0f * x, 2.0f * y, 2.0f * z, -xx);
}

// exact pd in 5 ops (reference-matching formula of rounds 3-24)
__device__ __forceinline__ float pd5(const float4 Qu, const float4 P)
{
    const float inner2 = __builtin_fmaf(Qu.z, P.z, __builtin_fmaf(Qu.y, P.y, __fmul_rn(Qu.x, P.x)));
    return __fadd_rn(__fadd_rn(Qu.w, inner2), P.w);
}

// ---------------- Kernel A: exact KNN, L2-direct, 4 queries/wave (r21/r23 champion: 67us) ----------------
// 512 threads = 8 waves x 4 queries = 32 rows/block; 1024 blocks. Candidates stream from
// L2 (xyzw = 512KB, resident in every XCD L2). Profile: VGPR=24, occ 72%, VALUBusy 88%.
// Threshold: FULL-SAMPLE pass 1; L = 16th-largest lane max (bitonic) => survivors
// {v>=L} contain the exact top-16, S>=16 guaranteed, E[S]~18. Pass 2: append survivor
// (value,index) via wave-private LDS atomic. Rank phase: rank-count under
// (value desc, index asc); ranks 0..15 emit == exact lax.top_k order.
// S>64 (prob ~0) -> exhaustive rescan from L2 (always correct).
__global__ __launch_bounds__(512, 4) void knn_kernel(const float4* __restrict__ xyzw, int* __restrict__ idxout)
{
    __shared__ float  dv[8][4][64];         // 8192 B
    __shared__ unsigned short di[8][4][64]; // 4096 B
    __shared__ int cnt[8][4];               // 128 B
    const int wave = threadIdx.x >> 6;
    const int lane = threadIdx.x & 63;
    const int rbase = blockIdx.x * 32 + wave * 4;     // 32 rows/block, one batch per block
    const float4* xb = xyzw + (size_t)(rbase >> 12) * Nn;
    const int n0 = rbase & (Nn - 1);

    float4 Qu[4];
#pragma unroll
    for (int q = 0; q < 4; ++q) {
        const float4 t = xb[n0 + q];
        Qu[q] = make_float4(0.5f * t.x, 0.5f * t.y, 0.5f * t.z, t.w);   // unscale: exact
    }
    if (lane < 4) cnt[wave][lane] = 0;

    // ---- pass 1: per-lane max of exact pd over all 4096 candidates (from L2) ----
    float m[4];
#pragma unroll
    for (int q = 0; q < 4; ++q) m[q] = -3.0e38f;
#pragma unroll 2
    for (int i = 0; i < 64; ++i) {
        const float4 P = xb[(i << 6) + lane];
#pragma unroll
        for (int q = 0; q < 4; ++q) m[q] = fmaxf(m[q], pd5(Qu[q], P));
    }

    // ---- bitonic sort (desc) of lane maxima; L = rank-15 ----
#pragma unroll
    for (int k = 2; k <= 64; k <<= 1) {
#pragma unroll
        for (int j = k >> 1; j > 0; j >>= 1) {
            const bool takeMax = ((lane & j) == 0) ^ ((lane & k) != 0);
#pragma unroll
            for (int q = 0; q < 4; ++q) {
                const float o = __shfl_xor(m[q], j);
                m[q] = takeMax ? fmaxf(m[q], o) : fminf(m[q], o);
            }
        }
    }
    float L[4];
#pragma unroll
    for (int q = 0; q < 4; ++q) L[q] = __shfl(m[q], 15);

    // ---- pass 2: exact pd from L2; append survivors (wave-private lists) ----
#pragma unroll 2
    for (int i = 0; i < 64; ++i) {
        const float4 P = xb[(i << 6) + lane];
        const int id = (i << 6) + lane;
#pragma unroll
        for (int q = 0; q < 4; ++q) {
            const float v = pd5(Qu[q], P);
            if (v >= L[q]) {
                const int pos = atomicAdd(&cnt[wave][q], 1);
                if (pos < 64) { dv[wave][q][pos] = v; di[wave][q][pos] = (unsigned short)id; }
            }
        }
    }

    // ---- rank-count selection + output ----
#pragma unroll
    for (int q = 0; q < 4; ++q) {
        const int S = cnt[wave][q];
        if (S <= 64) {   // S >= 16 guaranteed by construction (full-sample L)
            const float myv = dv[wave][q][lane];
            const int   myi = di[wave][q][lane];
            int rank = 0;
            for (int i = 0; i < S; ++i) {
                const float ov = dv[wave][q][i];
                const int   oi = di[wave][q][i];
                rank += ((ov > myv) || (ov == myv && oi < myi)) ? 1 : 0;
            }
            if (lane < S && rank < Kn) idxout[(size_t)(rbase + q) * Kn + rank] = myi;
        } else {
            float prevv = 3.0e38f; int previ = -1;
            int sel = 0;
            for (int it = 0; it < Kn; ++it) {
                float bv = -3.0e38f; int bm = 0x7FFFFFFF;
                for (int i = 0; i < 64; ++i) {
                    const float4 P = xb[(i << 6) + lane];
                    const int id = (i << 6) + lane;
                    const float v = pd5(Qu[q], P);
                    const bool after = (v < prevv) || (v == prevv && id > previ);
                    if (after && (v > bv || (v == bv && id < bm))) { bv = v; bm = id; }
                }
#pragma unroll
                for (int off = 32; off; off >>= 1) {
                    const float ov = __shfl_xor(bv, off);
                    const int   om = __shfl_xor(bm, off);
                    if (ov > bv || (ov == bv && om < bm)) { bv = ov; bm = om; }
                }
                if (lane == it) sel = bm;
                prevv = bv; previ = bm;
            }
            if (lane < Kn) idxout[(size_t)(rbase + q) * Kn + lane] = sel;
        }
    }
}

// ---------------- Kernel B0: M = Wq^T @ Wk, v = bq @ Wk ----------------
__global__ __launch_bounds__(128) void prep_kernel(const float* __restrict__ Wq, const float* __restrict__ bq,
                                                   const float* __restrict__ Wk, const float* __restrict__ bk,
                                                   float* __restrict__ M, float* __restrict__ v)
{
    const int dp = blockIdx.x;
    const int d  = threadIdx.x;
    float acc = 0.f;
    for (int e = 0; e < Dn; ++e) acc = fmaf(Wq[e * Dn + dp], Wk[e * Dn + d], acc);
    M[dp * Dn + d] = acc;
    if (dp == 0) {
        float a = 0.f;
        for (int e = 0; e < Dn; ++e) a = fmaf(bq[e], Wk[e * Dn + d], a);
        v[d] = a;
    }
}

// ---------------- Kernel B: t16 = half(concat @ M + v); also emits c16 = half(concat) ----------------
__global__ __launch_bounds__(256) void tmat_kernel(const float* __restrict__ concat, const float* __restrict__ M,
                                                   const float* __restrict__ vvec, __half* __restrict__ t16,
                                                   __half* __restrict__ c16)
{
    __shared__ float As[64][33];
    __shared__ float Ms[32][128];
    const int tid = threadIdx.x;
    const int row0 = blockIdx.x * 64;
    const int tx = tid & 15;
    const int ty = tid >> 4;
    float acc[4][8];
#pragma unroll
    for (int r = 0; r < 4; ++r)
#pragma unroll
        for (int j = 0; j < 8; ++j) acc[r][j] = 0.f;

    for (int kc = 0; kc < 4; ++kc) {
        const int k0 = kc * 32;
        __syncthreads();
#pragma unroll
        for (int p = 0; p < 8; ++p) {
            const int e = p * 256 + tid;
            const int r = e >> 5, kk = e & 31;
            const float val = concat[(size_t)(row0 + r) * Dn + k0 + kk];
            As[r][kk] = val;
            c16[(size_t)(row0 + r) * Dn + k0 + kk] = __float2half(val);
        }
#pragma unroll
        for (int p = 0; p < 16; ++p) {
            const int e = p * 256 + tid;
            const int kk = e >> 7, dd = e & 127;
            Ms[kk][dd] = M[(k0 + kk) * Dn + dd];
        }
        __syncthreads();
#pragma unroll
        for (int k = 0; k < 32; ++k) {
            const float4 mA = *(const float4*)(&Ms[k][tx * 8]);
            const float4 mB = *(const float4*)(&Ms[k][tx * 8 + 4]);
            const float mj[8] = {mA.x, mA.y, mA.z, mA.w, mB.x, mB.y, mB.z, mB.w};
#pragma unroll
            for (int r = 0; r < 4; ++r) {
                const float av = As[ty * 4 + r][k];
#pragma unroll
                for (int j = 0; j < 8; ++j) acc[r][j] = fmaf(av, mj[j], acc[r][j]);
            }
        }
    }
    float vv[8];
#pragma unroll
    for (int j = 0; j < 8; ++j) vv[j] = vvec[tx * 8 + j];
#pragma unroll
    for (int r = 0; r < 4; ++r) {
        __half h[8];
#pragma unroll
        for (int j = 0; j < 8; ++j) h[j] = __float2half(acc[r][j] + vv[j]);
        *(uint4*)(&t16[(size_t)(row0 + ty * 4 + r) * Dn + tx * 8]) = *(const uint4*)h;   // 8 halves = 16B
    }
}

// ---------------- Kernel C: transpose fp4_features [B,C,N] -> featT16 [B,N,C] (half) ----------------
__global__ __launch_bounds__(256) void transpose_kernel(const float* __restrict__ feat, __half* __restrict__ featT16)
{
    __shared__ float tile[32][33];
    const int n0 = blockIdx.x * 32;
    const int c0 = blockIdx.y * 32;
    const int b  = blockIdx.z;
    const int ln = threadIdx.x & 31, lg = threadIdx.x >> 5;
    const float* fb = feat + (size_t)b * Cn * Nn;
#pragma unroll
    for (int p = 0; p < 4; ++p) {
        const int c = lg + p * 8;
        tile[c][ln] = fb[(size_t)(c0 + c) * Nn + n0 + ln];
    }
    __syncthreads();
    __half* ob = featT16 + (size_t)b * Nn * Cn;
#pragma unroll
    for (int p = 0; p < 4; ++p) {
        const int nn = lg + p * 8;
        ob[(size_t)(n0 + nn) * Cn + c0 + ln] = __float2half(tile[ln][nn]);
    }
}

// ---------------- Kernel D: fused scores + softmax + aggregation; (256,8) occupancy target ----------------
// Latency-bound gather kernel (VALUBusy 14%, occ 44% at default target). (256,8) requests
// 8 waves/EU (32/CU); VGPR cap 2048/32=64 >= current 48 -> no spill risk. Cross-pt ILP
// structure from r24 retained. fp16 operands, fp32 accumulation, XCD-chunked swizzle.
__global__ __launch_bounds__(256, 8) void fused_kernel(const __half* __restrict__ c16, const __half* __restrict__ t16,
                                                       const __half* __restrict__ featT16, const int* __restrict__ knn,
                                                       float* __restrict__ out)
{
    __shared__ float outs[16][260];
    const int wave = threadIdx.x >> 6;
    const int lane = threadIdx.x & 63;
    const int j    = lane & 15;         // neighbor task
    const int sseg = lane >> 4;         // d-segment: d in [sseg*32, sseg*32+32)
    const int swz  = (blockIdx.x & 7) * 256 + (blockIdx.x >> 3);   // XCD-chunked remap
    const int rbase = swz * 16;
    const int b = rbase >> 12;          // all 16 rows of this block share one batch
    const float scale = 0.08838834764831845f;  // 1/sqrt(128)

    // ---- phase 1a: neighbor ids + score dots for all 4 pts (independent chains) ----
    int ij[4];
    float p[4];
#pragma unroll
    for (int pt = 0; pt < 4; ++pt) {
        const int row = rbase + wave * 4 + pt;
        ij[pt] = knn[row * Kn + j];
    }
#pragma unroll
    for (int pt = 0; pt < 4; ++pt) {
        const int row = rbase + wave * 4 + pt;
        const __half* trow = t16 + (size_t)row * Dn + sseg * 32;
        const __half* cj   = c16 + ((size_t)(b << 12) + ij[pt]) * Dn + sseg * 32;
        float acc = 0.f;
#pragma unroll
        for (int m = 0; m < 4; ++m) {
            const uint4 tv = *(const uint4*)(trow + m * 8);
            const uint4 cv = *(const uint4*)(cj + m * 8);
            const __half2* th = (const __half2*)&tv;
            const __half2* ch = (const __half2*)&cv;
#pragma unroll
            for (int e = 0; e < 4; ++e) {
                const float2 tf = __half22float2(th[e]);
                const float2 cf = __half22float2(ch[e]);
                acc = fmaf(tf.x, cf.x, acc);
                acc = fmaf(tf.y, cf.y, acc);
            }
        }
        p[pt] = acc;
    }

    // ---- phase 1b: cross-segment reduce + softmax, 4 pts interleaved ----
#pragma unroll
    for (int pt = 0; pt < 4; ++pt) p[pt] += __shfl_xor(p[pt], 16);
#pragma unroll
    for (int pt = 0; pt < 4; ++pt) { p[pt] += __shfl_xor(p[pt], 32); p[pt] *= scale; }

    float mx[4];
#pragma unroll
    for (int pt = 0; pt < 4; ++pt) mx[pt] = p[pt];
#pragma unroll
    for (int off = 1; off <= 8; off <<= 1)
#pragma unroll
        for (int pt = 0; pt < 4; ++pt) mx[pt] = fmaxf(mx[pt], __shfl_xor(mx[pt], off));

    float a[4], sum[4];
#pragma unroll
    for (int pt = 0; pt < 4; ++pt) { a[pt] = __expf(p[pt] - mx[pt]); sum[pt] = a[pt]; }
#pragma unroll
    for (int off = 1; off <= 8; off <<= 1)
#pragma unroll
        for (int pt = 0; pt < 4; ++pt) sum[pt] += __shfl_xor(sum[pt], off);
#pragma unroll
    for (int pt = 0; pt < 4; ++pt) a[pt] /= sum[pt];

    // ---- phase 2: feature gather, 4 pts interleaved (4x loads in flight per jj) ----
    float4 oacc[4];
#pragma unroll
    for (int pt = 0; pt < 4; ++pt) oacc[pt] = make_float4(0.f, 0.f, 0.f, 0.f);
#pragma unroll
    for (int jj = 0; jj < 16; ++jj) {
#pragma unroll
        for (int pt = 0; pt < 4; ++pt) {
            const float aj = __shfl(a[pt], jj);
            const int   xj = __shfl(ij[pt], jj);
            const uint2 fv = *(const uint2*)(featT16 + ((size_t)(b << 12) + xj) * Cn + lane * 4);
            const __half2* fh = (const __half2*)&fv;
            const float2 f0 = __half22float2(fh[0]);
            const float2 f1 = __half22float2(fh[1]);
            oacc[pt].x = fmaf(aj, f0.x, oacc[pt].x);
            oacc[pt].y = fmaf(aj, f0.y, oacc[pt].y);
            oacc[pt].z = fmaf(aj, f1.x, oacc[pt].z);
            oacc[pt].w = fmaf(aj, f1.y, oacc[pt].w);
        }
    }
#pragma unroll
    for (int pt = 0; pt < 4; ++pt)
        *(float4*)(&outs[wave * 4 + pt][lane * 4]) = oacc[pt];
    __syncthreads();

    const int n0 = rbase & (Nn - 1);
#pragma unroll
    for (int p2 = 0; p2 < 16; ++p2) {
        const int c  = (threadIdx.x >> 4) + p2 * 16;
        const int nn = threadIdx.x & 15;
        out[((size_t)b * Cn + c) * Nn + n0 + nn] = outs[nn][c];
    }
}

extern "C" void kernel_launch(void* const* d_in, const int* in_sizes, int n_in,
                              void* d_out, int out_size, void* d_ws, size_t ws_size,
                              hipStream_t stream) {
    const float* xyz    = (const float*)d_in[0];   // [B,N,3]
    const float* feat   = (const float*)d_in[1];   // [B,C,N]
    const float* concat = (const float*)d_in[2];   // [B,N,D]
    const float* Wq     = (const float*)d_in[3];
    const float* bq     = (const float*)d_in[4];
    const float* Wk     = (const float*)d_in[5];
    const float* bk     = (const float*)d_in[6];
    float* out = (float*)d_out;
    float* ws  = (float*)d_ws;

    // workspace layout (float units), offsets 16B-aligned
    float*  M       = ws;                       // 16384
    float*  v       = ws + 16512;               // 128
    int*    idx     = (int*)(ws + 16704);       // 32768*16 ints -> 524288
    __half* t16     = (__half*)(ws + 540992);   // 4,194,304 halves
    __half* c16     = (__half*)(ws + 2638144);  // 4,194,304 halves
    __half* featT16 = (__half*)(ws + 4735296);  // 8,388,608 halves
    float4* xyzw    = (float4*)(ws + 8929600);  // 32768 float4
    // total ~9.06M floats = 36.2 MB

    hipLaunchKernelGGL(pack_kernel,      dim3(128),        dim3(256), 0, stream, xyz, xyzw);
    hipLaunchKernelGGL(prep_kernel,      dim3(128),        dim3(128), 0, stream, Wq, bq, Wk, bk, M, v);
    hipLaunchKernelGGL(knn_kernel,       dim3(1024),       dim3(512), 0, stream, xyzw, idx);
    hipLaunchKernelGGL(tmat_kernel,      dim3(512),        dim3(256), 0, stream, concat, M, v, t16, c16);
    hipLaunchKernelGGL(transpose_kernel, dim3(128, 8, 8),  dim3(256), 0, stream, feat, featT16);
    hipLaunchKernelGGL(fused_kernel,     dim3(2048),       dim3(256), 0, stream, c16, t16, featT16, idx, out);
}